// Round 13
// baseline (944.650 us; speedup 1.0000x reference)
//
#include <hip/hip_runtime.h>
#include <hip/hip_bf16.h>
#include <stdint.h>

#define B_SZ 256
#define H_SZ 1024
#define NG   4096   // 4*H
#define F_SZ 32
#define T_SZ 96

typedef __attribute__((ext_vector_type(8))) short short8;
typedef __attribute__((ext_vector_type(4))) float f32x4;

__device__ __forceinline__ unsigned short f2bf(float x) {
  unsigned int u = __float_as_uint(x);
  u += 0x7fffu + ((u >> 16) & 1u);   // RNE
  return (unsigned short)(u >> 16);
}
__device__ __forceinline__ float sigf(float x) {
  float e = __expf(-x);
  return __builtin_amdgcn_rcpf(1.f + e);
}
__device__ __forceinline__ float tanh_fast(float x) {
  float e = __expf(-2.f * fabsf(x));
  float t = (1.f - e) * __builtin_amdgcn_rcpf(1.f + e);
  return copysignf(t, x);
}
// SC0 staging load: L1-bypass, L2-coherent (r7-verified protocol)
__device__ __forceinline__ void stage16c(const void* g, void* l) {
  __builtin_amdgcn_global_load_lds(
      (const __attribute__((address_space(1))) void*)g,
      (__attribute__((address_space(3))) void*)l, 16, 0, 1 /*sc0*/);
}
__device__ __forceinline__ short8 u4s8(uint4 v) {
  union { uint4 u; short8 s; } c; c.u = v; return c.s;
}

// ---------------------------------------------------------------------------
// Prep: WeffT[n][k] = (W_h + W_dense@W_x)^T, WhT[n][k], WdT[f][k] (bf16),
// single pass over W_h. Block 512: WdT + zero counters/xcctab.
// ---------------------------------------------------------------------------
__global__ __launch_bounds__(256) void k_prep_w(
    const float* __restrict__ Wx, const float* __restrict__ Wh,
    const float* __restrict__ Wd,
    unsigned short* __restrict__ WeffT, unsigned short* __restrict__ WhT,
    unsigned short* __restrict__ WdT, unsigned int* __restrict__ flags)
{
  int tid = threadIdx.x;
  if (blockIdx.x == 512) {               // WdT; zero counters + xcctab
    for (int i = 0; i < 33; ++i) flags[i * 256 + tid] = 0u;
    for (int i = 0; i < 128; ++i) {
      int idx = i * 256 + tid;
      int f = idx >> 10, k = idx & 1023;
      WdT[idx] = f2bf(Wd[k * 32 + f]);
    }
    return;
  }
  __shared__ float wx[32 * 256];              // 32 KB: W_x[f][n-tile]
  __shared__ unsigned short resE[32 * 256];   // 16 KB
  __shared__ unsigned short resH[32 * 256];   // 16 KB
  int kt = blockIdx.x & 31, nt = blockIdx.x >> 5;
  int k0 = kt * 32, n0 = nt * 256;
  for (int i = 0; i < 32; ++i) {
    int lin = i * 256 + tid;
    wx[lin] = Wx[(size_t)(lin >> 8) * NG + n0 + (lin & 255)];
  }
  __syncthreads();
  for (int kr = 0; kr < 32; ++kr) {
    int k = k0 + kr;
    float v = Wh[(size_t)k * NG + n0 + tid];
    float acc = 0.f;
#pragma unroll
    for (int f = 0; f < 32; ++f) acc += Wd[k * 32 + f] * wx[f * 256 + tid];
    resH[kr * 256 + tid] = f2bf(v);
    resE[kr * 256 + tid] = f2bf(v + acc);
  }
  __syncthreads();
#pragma unroll
  for (int pass = 0; pass < 2; ++pass) {
    const unsigned short* res = pass ? resH : resE;
    unsigned short* dst = (pass ? WhT : WeffT) + (size_t)(n0 + tid) * H_SZ + k0;
    unsigned int vals[16];
#pragma unroll
    for (int p = 0; p < 16; ++p)
      vals[p] = (unsigned int)res[(2 * p) * 256 + tid] |
                ((unsigned int)res[(2 * p + 1) * 256 + tid] << 16);
#pragma unroll
    for (int qd = 0; qd < 4; ++qd) {
      uint4 v4; v4.x = vals[4*qd]; v4.y = vals[4*qd+1]; v4.z = vals[4*qd+2]; v4.w = vals[4*qd+3];
      ((uint4*)dst)[qd] = v4;
    }
  }
}

// ---------------------------------------------------------------------------
// Persistent LSTM, dual-stream (r12 data path, verified), SEGMENTED:
// runs steps [jstart, jend]; c-state spilled/reloaded via cws; h/flags
// continue across launches. amp=1 adds ONE extra full barrier generation
// per step (ctrX) — pure measurement of barrier round-trip + skew cost.
// ---------------------------------------------------------------------------
__global__ __launch_bounds__(256, 1) void k_persist(
    const unsigned short* __restrict__ WeffT,
    const unsigned short* __restrict__ WhT,
    const float* __restrict__ x0,
    const float* __restrict__ h0,
    const float* __restrict__ c0,
    const float* __restrict__ Wx,
    const float* __restrict__ bvec,
    const float* __restrict__ bd,
    const unsigned short* __restrict__ WdT,
    unsigned short* __restrict__ hbuf0,
    unsigned short* __restrict__ hbuf1,
    float* __restrict__ out,
    unsigned int* __restrict__ flags,
    float* __restrict__ cws,
    int jstart, int jend, int amp)
{
  const int b = blockIdx.x;
  const int xcd = b & 7, slot = b >> 3;    // data-layout grouping
  const int m0A = xcd << 5;                // stream A: rows m0A..m0A+15
  const int m0B = m0A + 16;                // stream B: rows m0B..m0B+15
  const int nh = slot << 5;                // 32 h-cols per block
  const int tid = threadIdx.x, lane = tid & 63, g = tid >> 6;  // wave = gate

  __shared__ unsigned short AbA[32 * 512]; // 32 KB stream-A h tile (swizzled)
  __shared__ unsigned short AbB[32 * 512]; // 32 KB stream-B h tile
  __shared__ float zldsA[4][16][33];       // gate exchange A
  __shared__ float zldsB[4][16][33];       // gate exchange B
  __shared__ float ypA[8][32];             // y partials A
  __shared__ float ypB[8][32];             // y partials B

  unsigned int* xcctab = flags + 8192;
  unsigned int* ctrA = flags + (xcd << 4);
  unsigned int* ctrB = flags + 2048 + (xcd << 4);
  unsigned int* ctrX = flags + 4096 + (xcd << 4);
  unsigned int myxcc;
  asm volatile("s_getreg_b32 %0, hwreg(HW_REG_XCC_ID)" : "=s"(myxcc));
  myxcc &= 15u;

  int xgen = 0;
  bool pure = false;
  float cregA[2], cregB[2];

  if (jstart == 0) {
    // --- init: h0 slices -> bf16, c0 -> registers ---
#pragma unroll
    for (int e = 0; e < 2; ++e) {
      int idx = e * 256 + tid;
      int m = idx >> 5, cc = idx & 31;
      size_t giA = (size_t)(m0A + m) * H_SZ + nh + cc;
      size_t giB = (size_t)(m0B + m) * H_SZ + nh + cc;
      hbuf0[giA] = f2bf(h0[giA]);
      hbuf0[giB] = f2bf(h0[giB]);
      cregA[e] = c0[giA];
      cregB[e] = c0[giB];
    }
    __syncthreads();                       // per-wave vmcnt drained -> L2
    if (tid == 0) {
      __hip_atomic_store(&xcctab[b], myxcc, __ATOMIC_RELAXED,
                         __HIP_MEMORY_SCOPE_AGENT);
      __hip_atomic_fetch_add(ctrA, 1u, __ATOMIC_RELEASE, __HIP_MEMORY_SCOPE_AGENT);
      __hip_atomic_fetch_add(ctrB, 1u, __ATOMIC_RELEASE, __HIP_MEMORY_SCOPE_AGENT);
    }
  } else {
    // --- continuation: reload c, publish xcc, entry barrier, pure-detect ---
#pragma unroll
    for (int e = 0; e < 2; ++e) {
      int idx = e * 256 + tid;
      int m = idx >> 5, cc = idx & 31;
      cregA[e] = cws[(size_t)(m0A + m) * H_SZ + nh + cc];
      cregB[e] = cws[(size_t)(m0B + m) * H_SZ + nh + cc];
    }
    if (tid == 0) {
      __hip_atomic_store(&xcctab[b], myxcc, __ATOMIC_RELAXED,
                         __HIP_MEMORY_SCOPE_AGENT);
      __hip_atomic_fetch_add(ctrX, 1u, __ATOMIC_RELEASE, __HIP_MEMORY_SCOPE_AGENT);
    }
    ++xgen;
    while (__hip_atomic_load(ctrX, __ATOMIC_RELAXED,
                             __HIP_MEMORY_SCOPE_AGENT) < 32u * (unsigned)xgen) { }
    __builtin_amdgcn_fence(__ATOMIC_ACQUIRE, "agent");
    bool eq = (__hip_atomic_load(&xcctab[((lane & 31) << 3) | xcd],
                                 __ATOMIC_RELAXED,
                                 __HIP_MEMORY_SCOPE_AGENT) == myxcc);
    pure = __all(eq);
  }

  // --- per-lane bias: bfv0/1 (steady), u0rA/B[chain][e] (step 0) ---
  const int col = lane & 15;
  const int kq = lane >> 4;
  const int n0c0 = (g << 10) + nh + col;       // chain 0 column
  const int n0c1 = n0c0 + 16;                  // chain 1 column
  float bfv0 = bvec[n0c0], bfv1 = bvec[n0c1];
  float u0rA[2][4], u0rB[2][4];
#pragma unroll
  for (int e = 0; e < 4; ++e) {
    u0rA[0][e] = bfv0; u0rA[1][e] = bfv1;
    u0rB[0][e] = bfv0; u0rB[1][e] = bfv1;
  }
  for (int f = 0; f < 32; ++f) {
    float wx0 = Wx[(size_t)f * NG + n0c0];
    float wx1 = Wx[(size_t)f * NG + n0c1];
    bfv0 += bd[f] * wx0; bfv1 += bd[f] * wx1;
#pragma unroll
    for (int e = 0; e < 4; ++e) {
      int row = (kq << 2) + e;
      float xA = x0[(m0A + row) * 32 + f];
      float xB = x0[(m0B + row) * 32 + f];
      u0rA[0][e] += xA * wx0; u0rA[1][e] += xA * wx1;
      u0rB[0][e] += xB * wx0; u0rB[1][e] += xB * wx1;
    }
  }

  // --- W fragments: 2 chains x 32 uint4 = 256 regs, pinned resident ---
  uint4 wr0[32], wr1[32];
  {
    const unsigned short* wbase = (jstart == 0) ? WhT : WeffT;
    const unsigned short* p0 = wbase + (size_t)n0c0 * H_SZ + (kq << 3);
    const unsigned short* p1 = wbase + (size_t)n0c1 * H_SZ + (kq << 3);
#pragma unroll
    for (int kk = 0; kk < 32; ++kk) {
      wr0[kk] = *(const uint4*)(p0 + kk * 32);
      wr1[kk] = *(const uint4*)(p1 + kk * 32);
    }
#pragma unroll
    for (int kk = 0; kk < 32; ++kk) {
      asm volatile("" : "+v"(wr0[kk].x), "+v"(wr0[kk].y),
                        "+v"(wr0[kk].z), "+v"(wr0[kk].w));
      asm volatile("" : "+v"(wr1[kk].x), "+v"(wr1[kk].y),
                        "+v"(wr1[kk].z), "+v"(wr1[kk].w));
    }
  }

  // staging addrs: chunk = 16 rows x 32 k (1 KB); pre-swizzled source
  const int srow = lane >> 2;                        // 0..15
  const int skg  = (lane & 3) ^ ((srow >> 1) & 3);   // XOR by (row>>1)&3
  const int sgoff = srow * H_SZ + (skg << 3);
  const int q = kq ^ ((col >> 1) & 3);
  const int aoff = col * 32 + (q << 3);
  const int yf = tid & 31, ykc = tid >> 5;
  const int yrow = slot & 15;
  const int ysw = (slot >> 1) & 3;
  const bool yIsA = (slot < 16);
  const unsigned short* wdp = WdT + (size_t)yf * H_SZ + ykc * 128;

  for (int j = jstart; j <= jend; ++j) {
    const unsigned int tgt = 32u * (unsigned)(j + 1);
    // ---- wait A ----
    while (__hip_atomic_load(ctrA, __ATOMIC_RELAXED,
                             __HIP_MEMORY_SCOPE_AGENT) < tgt) { }
    if (j == 0) {
      __builtin_amdgcn_fence(__ATOMIC_ACQUIRE, "agent");  // one-time L2 inv
      bool eq = (__hip_atomic_load(&xcctab[((lane & 31) << 3) | xcd],
                                   __ATOMIC_RELAXED,
                                   __HIP_MEMORY_SCOPE_AGENT) == myxcc);
      pure = __all(eq);
    } else if (!pure) {
      __builtin_amdgcn_fence(__ATOMIC_ACQUIRE, "agent");
    }
    const unsigned short* hp = (j & 1) ? hbuf1 : hbuf0;
    unsigned short* hn = (j & 1) ? hbuf0 : hbuf1;

    // ---- stage A (32 KB), slot-rotated chunk order ----
    {
      const unsigned short* srcb = hp + (size_t)m0A * H_SZ + sgoff;
#pragma unroll
      for (int it = 0; it < 8; ++it) {
        int c = (g + it * 4 + slot) & 31;
        stage16c(srcb + c * 32, &AbA[c * 512]);
      }
      __syncthreads();                     // AbA ready
    }

    // ---- wait B + early-issue stage B ----
    while (__hip_atomic_load(ctrB, __ATOMIC_RELAXED,
                             __HIP_MEMORY_SCOPE_AGENT) < tgt) { }
    if (!pure)
      __builtin_amdgcn_fence(__ATOMIC_ACQUIRE, "agent");
    {
      const unsigned short* srcb = hp + (size_t)m0B * H_SZ + sgoff;
#pragma unroll
      for (int it = 0; it < 8; ++it) {
        int c = (g + it * 4 + slot) & 31;
        stage16c(srcb + c * 32, &AbB[c * 512]);
      }
    }

    // ---- y-dot A ----
    if (j >= 1 && yIsA) {
      float acc = 0.f;
#pragma unroll
      for (int c2 = 0; c2 < 4; ++c2) {
        const unsigned short* ab = AbA + (ykc * 4 + c2) * 512 + yrow * 32;
#pragma unroll
        for (int p = 0; p < 4; ++p) {
          uint4 av = *(const uint4*)(ab + (p << 3));
          uint4 wv = *(const uint4*)(wdp + c2 * 32 + ((p ^ ysw) << 3));
          acc += __uint_as_float(av.x << 16) * __uint_as_float(wv.x << 16);
          acc += __uint_as_float(av.x & 0xffff0000u) * __uint_as_float(wv.x & 0xffff0000u);
          acc += __uint_as_float(av.y << 16) * __uint_as_float(wv.y << 16);
          acc += __uint_as_float(av.y & 0xffff0000u) * __uint_as_float(wv.y & 0xffff0000u);
          acc += __uint_as_float(av.z << 16) * __uint_as_float(wv.z << 16);
          acc += __uint_as_float(av.z & 0xffff0000u) * __uint_as_float(wv.z & 0xffff0000u);
          acc += __uint_as_float(av.w << 16) * __uint_as_float(wv.w << 16);
          acc += __uint_as_float(av.w & 0xffff0000u) * __uint_as_float(wv.w & 0xffff0000u);
        }
      }
      ypA[ykc][yf] = acc;
    }

    // ---- GEMM A ----
    if (j < T_SZ) {
      f32x4 c0E, c0O, c1E, c1O;
#pragma unroll
      for (int e = 0; e < 4; ++e) {
        c0E[e] = (j == 0) ? u0rA[0][e] : bfv0;
        c1E[e] = (j == 0) ? u0rA[1][e] : bfv1;
        c0O[e] = 0.f; c1O[e] = 0.f;
      }
#pragma unroll
      for (int kk = 0; kk < 32; kk += 2) {
        short8 a0 = *(const short8*)(AbA + kk * 512 + aoff);
        short8 a1 = *(const short8*)(AbA + (kk + 1) * 512 + aoff);
        c0E = __builtin_amdgcn_mfma_f32_16x16x32_bf16(a0, u4s8(wr0[kk]), c0E, 0, 0, 0);
        c1E = __builtin_amdgcn_mfma_f32_16x16x32_bf16(a0, u4s8(wr1[kk]), c1E, 0, 0, 0);
        c0O = __builtin_amdgcn_mfma_f32_16x16x32_bf16(a1, u4s8(wr0[kk + 1]), c0O, 0, 0, 0);
        c1O = __builtin_amdgcn_mfma_f32_16x16x32_bf16(a1, u4s8(wr1[kk + 1]), c1O, 0, 0, 0);
      }
#pragma unroll
      for (int e = 0; e < 4; ++e) {
        zldsA[g][(kq << 2) + e][col] = c0E[e] + c0O[e];
        zldsA[g][(kq << 2) + e][16 + col] = c1E[e] + c1O[e];
      }
    }
    __syncthreads();                       // zldsA+ypA ready; stage B drained

    if (j < T_SZ) {                        // cell update A
#pragma unroll
      for (int e = 0; e < 2; ++e) {
        int idx = e * 256 + tid;
        int m = idx >> 5, cc = idx & 31;
        float zi = zldsA[0][m][cc], zf = zldsA[1][m][cc];
        float zg = zldsA[2][m][cc], zo = zldsA[3][m][cc];
        float iv = sigf(zi), fv = sigf(zf), gv = tanh_fast(zg), ov = sigf(zo);
        float cn = fv * cregA[e] + iv * gv;
        cregA[e] = cn;
        hn[(size_t)(m0A + m) * H_SZ + nh + cc] = f2bf(ov * tanh_fast(cn));
      }
    }
    if (j >= 1 && yIsA && tid < 32) {
      float s = bd[tid];
#pragma unroll
      for (int kc = 0; kc < 8; ++kc) s += ypA[kc][tid];
      out[(size_t)(m0A + yrow) * (T_SZ * F_SZ) + (size_t)(j - 1) * F_SZ + tid] = s;
    }
    __syncthreads();                       // hA stores drained -> L2
    if (tid == 0 && j < T_SZ) {
      if (pure)
        __hip_atomic_fetch_add(ctrA, 1u, __ATOMIC_RELAXED, __HIP_MEMORY_SCOPE_AGENT);
      else
        __hip_atomic_fetch_add(ctrA, 1u, __ATOMIC_RELEASE, __HIP_MEMORY_SCOPE_AGENT);
    }

    // ==== stream B ====
    if (j >= 1 && !yIsA) {
      float acc = 0.f;
#pragma unroll
      for (int c2 = 0; c2 < 4; ++c2) {
        const unsigned short* ab = AbB + (ykc * 4 + c2) * 512 + yrow * 32;
#pragma unroll
        for (int p = 0; p < 4; ++p) {
          uint4 av = *(const uint4*)(ab + (p << 3));
          uint4 wv = *(const uint4*)(wdp + c2 * 32 + ((p ^ ysw) << 3));
          acc += __uint_as_float(av.x << 16) * __uint_as_float(wv.x << 16);
          acc += __uint_as_float(av.x & 0xffff0000u) * __uint_as_float(wv.x & 0xffff0000u);
          acc += __uint_as_float(av.y << 16) * __uint_as_float(wv.y << 16);
          acc += __uint_as_float(av.y & 0xffff0000u) * __uint_as_float(wv.y & 0xffff0000u);
          acc += __uint_as_float(av.z << 16) * __uint_as_float(wv.z << 16);
          acc += __uint_as_float(av.z & 0xffff0000u) * __uint_as_float(wv.z & 0xffff0000u);
          acc += __uint_as_float(av.w << 16) * __uint_as_float(wv.w << 16);
          acc += __uint_as_float(av.w & 0xffff0000u) * __uint_as_float(wv.w & 0xffff0000u);
        }
      }
      ypB[ykc][yf] = acc;
    }

    if (j < T_SZ) {
      f32x4 c0E, c0O, c1E, c1O;
#pragma unroll
      for (int e = 0; e < 4; ++e) {
        c0E[e] = (j == 0) ? u0rB[0][e] : bfv0;
        c1E[e] = (j == 0) ? u0rB[1][e] : bfv1;
        c0O[e] = 0.f; c1O[e] = 0.f;
      }
#pragma unroll
      for (int kk = 0; kk < 32; kk += 2) {
        short8 a0 = *(const short8*)(AbB + kk * 512 + aoff);
        short8 a1 = *(const short8*)(AbB + (kk + 1) * 512 + aoff);
        c0E = __builtin_amdgcn_mfma_f32_16x16x32_bf16(a0, u4s8(wr0[kk]), c0E, 0, 0, 0);
        c1E = __builtin_amdgcn_mfma_f32_16x16x32_bf16(a0, u4s8(wr1[kk]), c1E, 0, 0, 0);
        c0O = __builtin_amdgcn_mfma_f32_16x16x32_bf16(a1, u4s8(wr0[kk + 1]), c0O, 0, 0, 0);
        c1O = __builtin_amdgcn_mfma_f32_16x16x32_bf16(a1, u4s8(wr1[kk + 1]), c1O, 0, 0, 0);
      }
      if (j == 0) {                        // switch to folded weights (once)
        const unsigned short* p0 = WeffT + (size_t)n0c0 * H_SZ + (kq << 3);
        const unsigned short* p1 = WeffT + (size_t)n0c1 * H_SZ + (kq << 3);
#pragma unroll
        for (int kk = 0; kk < 32; ++kk) {
          wr0[kk] = *(const uint4*)(p0 + kk * 32);
          wr1[kk] = *(const uint4*)(p1 + kk * 32);
        }
#pragma unroll
        for (int kk = 0; kk < 32; ++kk) {
          asm volatile("" : "+v"(wr0[kk].x), "+v"(wr0[kk].y),
                            "+v"(wr0[kk].z), "+v"(wr0[kk].w));
          asm volatile("" : "+v"(wr1[kk].x), "+v"(wr1[kk].y),
                            "+v"(wr1[kk].z), "+v"(wr1[kk].w));
        }
      }
#pragma unroll
      for (int e = 0; e < 4; ++e) {
        zldsB[g][(kq << 2) + e][col] = c0E[e] + c0O[e];
        zldsB[g][(kq << 2) + e][16 + col] = c1E[e] + c1O[e];
      }
    }
    __syncthreads();                       // zldsB+ypB ready

    if (j < T_SZ) {                        // cell update B
#pragma unroll
      for (int e = 0; e < 2; ++e) {
        int idx = e * 256 + tid;
        int m = idx >> 5, cc = idx & 31;
        float zi = zldsB[0][m][cc], zf = zldsB[1][m][cc];
        float zg = zldsB[2][m][cc], zo = zldsB[3][m][cc];
        float iv = sigf(zi), fv = sigf(zf), gv = tanh_fast(zg), ov = sigf(zo);
        float cn = fv * cregB[e] + iv * gv;
        cregB[e] = cn;
        hn[(size_t)(m0B + m) * H_SZ + nh + cc] = f2bf(ov * tanh_fast(cn));
      }
    }
    if (j >= 1 && !yIsA && tid < 32) {
      float s = bd[tid];
#pragma unroll
      for (int kc = 0; kc < 8; ++kc) s += ypB[kc][tid];
      out[(size_t)(m0B + yrow) * (T_SZ * F_SZ) + (size_t)(j - 1) * F_SZ + tid] = s;
    }
    __syncthreads();                       // hB stores drained -> L2
    if (tid == 0 && j < T_SZ) {
      if (pure)
        __hip_atomic_fetch_add(ctrB, 1u, __ATOMIC_RELAXED, __HIP_MEMORY_SCOPE_AGENT);
      else
        __hip_atomic_fetch_add(ctrB, 1u, __ATOMIC_RELEASE, __HIP_MEMORY_SCOPE_AGENT);
    }

    // ---- AMP: one extra full barrier generation (measurement only) ----
    if (amp && j < T_SZ) {
      ++xgen;
      if (tid == 0)
        __hip_atomic_fetch_add(ctrX, 1u, __ATOMIC_RELAXED, __HIP_MEMORY_SCOPE_AGENT);
      while (__hip_atomic_load(ctrX, __ATOMIC_RELAXED,
                               __HIP_MEMORY_SCOPE_AGENT) < 32u * (unsigned)xgen) { }
    }
  }

  // --- spill c-state for the next segment ---
  if (jend < T_SZ) {
#pragma unroll
    for (int e = 0; e < 2; ++e) {
      int idx = e * 256 + tid;
      int m = idx >> 5, cc = idx & 31;
      cws[(size_t)(m0A + m) * H_SZ + nh + cc] = cregA[e];
      cws[(size_t)(m0B + m) * H_SZ + nh + cc] = cregB[e];
    }
  }
}

// ---------------------------------------------------------------------------
extern "C" void kernel_launch(void* const* d_in, const int* in_sizes, int n_in,
                              void* d_out, int out_size, void* d_ws, size_t ws_size,
                              hipStream_t stream)
{
  const float* x0 = (const float*)d_in[0];   // (256,1,32)
  const float* h0 = (const float*)d_in[1];   // (256,1024)
  const float* c0 = (const float*)d_in[2];
  // d_in[3] targets unused
  const float* Wx = (const float*)d_in[4];   // (32,4096)
  const float* Wh = (const float*)d_in[5];   // (1024,4096)
  const float* bv = (const float*)d_in[6];   // (4096)
  const float* Wd = (const float*)d_in[7];   // (1024,32)
  const float* bd = (const float*)d_in[8];   // (32)
  float* out = (float*)d_out;                // (256,96,32) fp32

  char* p = (char*)d_ws;
  unsigned short* WeffT = (unsigned short*)p; p += (size_t)NG * H_SZ * 2;   // 8 MB
  unsigned short* WhT   = (unsigned short*)p; p += (size_t)NG * H_SZ * 2;   // 8 MB
  unsigned short* WdT   = (unsigned short*)p; p += (size_t)F_SZ * H_SZ * 2; // 64 KB
  unsigned short* hb0   = (unsigned short*)p; p += (size_t)B_SZ * H_SZ * 2; // 512 KB
  unsigned short* hb1   = (unsigned short*)p; p += (size_t)B_SZ * H_SZ * 2; // 512 KB
  unsigned int* flags   = (unsigned int*)p;  p += 8704 * 4;                 // 34 KB
  float* cws            = (float*)p;         p += (size_t)B_SZ * H_SZ * 4;  // 1 MB
  (void)ws_size; (void)in_sizes; (void)n_in; (void)out_size;

  k_prep_w<<<dim3(513), dim3(256), 0, stream>>>(Wx, Wh, Wd, WeffT, WhT, WdT, flags);

  // segment 1: steps 0..47, baseline
  k_persist<<<dim3(256), dim3(256), 0, stream>>>(
      WeffT, WhT, x0, h0, c0, Wx, bv, bd, WdT, hb0, hb1, out, flags, cws,
      0, 47, 0);
  // segment 2: steps 48..96, + one extra barrier generation per step
  k_persist<<<dim3(256), dim3(256), 0, stream>>>(
      WeffT, WhT, x0, h0, c0, Wx, bv, bd, WdT, hb0, hb1, out, flags, cws,
      48, 96, 1);
}

// Round 14
// 823.959 us; speedup vs baseline: 1.1465x; 1.1465x over previous
//
#include <hip/hip_runtime.h>
#include <hip/hip_bf16.h>
#include <stdint.h>

#define B_SZ 256
#define H_SZ 1024
#define NG   4096   // 4*H
#define F_SZ 32
#define T_SZ 96

typedef __attribute__((ext_vector_type(8))) short short8;
typedef __attribute__((ext_vector_type(4))) float f32x4;

__device__ __forceinline__ unsigned short f2bf(float x) {
  unsigned int u = __float_as_uint(x);
  u += 0x7fffu + ((u >> 16) & 1u);   // RNE
  return (unsigned short)(u >> 16);
}
__device__ __forceinline__ float sigf(float x) {
  float e = __expf(-x);
  return __builtin_amdgcn_rcpf(1.f + e);
}
__device__ __forceinline__ float tanh_fast(float x) {
  float e = __expf(-2.f * fabsf(x));
  float t = (1.f - e) * __builtin_amdgcn_rcpf(1.f + e);
  return copysignf(t, x);
}
// SC0 staging load: L1-bypass, L2-coherent (r7-verified protocol)
__device__ __forceinline__ void stage16c(const void* g, void* l) {
  __builtin_amdgcn_global_load_lds(
      (const __attribute__((address_space(1))) void*)g,
      (__attribute__((address_space(3))) void*)l, 16, 0, 1 /*sc0*/);
}
__device__ __forceinline__ short8 u4s8(uint4 v) {
  union { uint4 u; short8 s; } c; c.u = v; return c.s;
}

// ---------------------------------------------------------------------------
// Prep: WeffT[n][k] = (W_h + W_dense@W_x)^T, WhT[n][k], WdT[f][k] (bf16),
// single pass over W_h. Block 512: WdT + zero arrivals/epochs/xcctab.
// ---------------------------------------------------------------------------
__global__ __launch_bounds__(256) void k_prep_w(
    const float* __restrict__ Wx, const float* __restrict__ Wh,
    const float* __restrict__ Wd,
    unsigned short* __restrict__ WeffT, unsigned short* __restrict__ WhT,
    unsigned short* __restrict__ WdT, unsigned int* __restrict__ flags)
{
  int tid = threadIdx.x;
  if (blockIdx.x == 512) {               // WdT; zero arrA/arrB/epochs/xcctab
    for (int i = 0; i < 34; ++i) flags[i * 256 + tid] = 0u;
    for (int i = 0; i < 128; ++i) {
      int idx = i * 256 + tid;
      int f = idx >> 10, k = idx & 1023;
      WdT[idx] = f2bf(Wd[k * 32 + f]);
    }
    return;
  }
  __shared__ float wx[32 * 256];              // 32 KB: W_x[f][n-tile]
  __shared__ unsigned short resE[32 * 256];   // 16 KB
  __shared__ unsigned short resH[32 * 256];   // 16 KB
  int kt = blockIdx.x & 31, nt = blockIdx.x >> 5;
  int k0 = kt * 32, n0 = nt * 256;
  for (int i = 0; i < 32; ++i) {
    int lin = i * 256 + tid;
    wx[lin] = Wx[(size_t)(lin >> 8) * NG + n0 + (lin & 255)];
  }
  __syncthreads();
  for (int kr = 0; kr < 32; ++kr) {
    int k = k0 + kr;
    float v = Wh[(size_t)k * NG + n0 + tid];
    float acc = 0.f;
#pragma unroll
    for (int f = 0; f < 32; ++f) acc += Wd[k * 32 + f] * wx[f * 256 + tid];
    resH[kr * 256 + tid] = f2bf(v);
    resE[kr * 256 + tid] = f2bf(v + acc);
  }
  __syncthreads();
#pragma unroll
  for (int pass = 0; pass < 2; ++pass) {
    const unsigned short* res = pass ? resH : resE;
    unsigned short* dst = (pass ? WhT : WeffT) + (size_t)(n0 + tid) * H_SZ + k0;
    unsigned int vals[16];
#pragma unroll
    for (int p = 0; p < 16; ++p)
      vals[p] = (unsigned int)res[(2 * p) * 256 + tid] |
                ((unsigned int)res[(2 * p + 1) * 256 + tid] << 16);
#pragma unroll
    for (int qd = 0; qd < 4; ++qd) {
      uint4 v4; v4.x = vals[4*qd]; v4.y = vals[4*qd+1]; v4.z = vals[4*qd+2]; v4.w = vals[4*qd+3];
      ((uint4*)dst)[qd] = v4;
    }
  }
}

// ---------------------------------------------------------------------------
// Persistent LSTM, dual-stream, 8 waves (the 714us-best base), with an
// AGGREGATOR-BROADCAST barrier. r13 amp-experiment measured: one barrier
// generation (32 same-line RMWs + detection) = ~4.5us; the r7-r11 flag-array
// variant floods L2 with 32-line gathers from 256 waves/XCD. New barrier:
//  - arrival: RELAXED store to own 64B line (parallel, no RMW)
//  - aggregate: group slot-0 block, wave 0 only, polls the 32 arrival lines,
//    then stores one per-group epoch word
//  - wait: everyone spins on the single epoch line (broadcast read, sleep 2)
// Data path, staging (SC0), pure-XCD protocol identical to the 714us kernel.
// ---------------------------------------------------------------------------
__global__ __launch_bounds__(512, 2) void k_persist(
    const unsigned short* __restrict__ WeffT,
    const unsigned short* __restrict__ WhT,
    const float* __restrict__ x0,
    const float* __restrict__ h0,
    const float* __restrict__ c0,
    const float* __restrict__ Wx,
    const float* __restrict__ bvec,
    const float* __restrict__ bd,
    const unsigned short* __restrict__ WdT,
    unsigned short* __restrict__ hbuf0,
    unsigned short* __restrict__ hbuf1,
    float* __restrict__ out,
    unsigned int* __restrict__ flags)
{
  const int b = blockIdx.x;
  const int xcd = b & 7, slot = b >> 3;    // data-layout grouping
  const int m0A = xcd << 5;                // stream A: rows m0A..m0A+15
  const int m0B = m0A + 16;                // stream B: rows m0B..m0B+15
  const int nh = slot << 5;                // 32 h-cols per block
  const int tid = threadIdx.x, lane = tid & 63, w = tid >> 6;
  const int g = w >> 1;                    // gate
  const int nhh = (w & 1) << 4;            // 16-col half

  __shared__ unsigned short AbA[32 * 512]; // 32 KB stream-A h tile (swizzled)
  __shared__ unsigned short AbB[32 * 512]; // 32 KB stream-B h tile
  __shared__ float zldsA[4][16][33];       // gate exchange A
  __shared__ float zldsB[4][16][33];       // gate exchange B
  __shared__ float ypA[16][32];            // y partials A
  __shared__ float ypB[16][32];            // y partials B

  // flags layout (words): arrA [0..4095], arrB [4096..8191],
  // epochA [8192 + g*16], epochB [8320 + g*16], xcctab [8448..8703]
  unsigned int* xcctab = flags + 8448;
  unsigned int* epochA = flags + 8192 + (xcd << 4);
  unsigned int* epochB = flags + 8320 + (xcd << 4);
  unsigned int myxcc;
  asm volatile("s_getreg_b32 %0, hwreg(HW_REG_XCC_ID)" : "=s"(myxcc));
  myxcc &= 15u;

  // --- init: h0 slices -> bf16, c0 -> registers (1 cell/thread/stream) ---
  float cregA, cregB;
  {
    int m = tid >> 5, cc = tid & 31;
    size_t giA = (size_t)(m0A + m) * H_SZ + nh + cc;
    size_t giB = (size_t)(m0B + m) * H_SZ + nh + cc;
    hbuf0[giA] = f2bf(h0[giA]);
    hbuf0[giB] = f2bf(h0[giB]);
    cregA = c0[giA];
    cregB = c0[giB];
  }
  __syncthreads();                         // per-wave vmcnt drained -> L2
  unsigned int* arrA = flags + (((xcd << 5) | slot) << 4);   // 64B stride
  unsigned int* arrB = arrA + 4096;
  if (tid == 0) {
    __hip_atomic_store(&xcctab[b], myxcc, __ATOMIC_RELAXED,
                       __HIP_MEMORY_SCOPE_AGENT);
    __hip_atomic_store(arrA, 1u, __ATOMIC_RELEASE, __HIP_MEMORY_SCOPE_AGENT);
    __hip_atomic_store(arrB, 1u, __ATOMIC_RELEASE, __HIP_MEMORY_SCOPE_AGENT);
  }

  // --- per-lane bias: bfv (steady-state), u0r[mf][e] (step 0) ---
  const int col = lane & 15;
  const int kq = lane >> 4;
  const int n0a = (g << 10) + nh + nhh + col;
  float bfv = bvec[n0a];
  float u0rA[4], u0rB[4];
#pragma unroll
  for (int e = 0; e < 4; ++e) { u0rA[e] = bfv; u0rB[e] = bfv; }
  for (int f = 0; f < 32; ++f) {
    float wxf = Wx[(size_t)f * NG + n0a];
    bfv += bd[f] * wxf;
#pragma unroll
    for (int e = 0; e < 4; ++e) {
      int row = (kq << 2) + e;
      u0rA[e] += x0[(m0A + row) * 32 + f] * wxf;
      u0rB[e] += x0[(m0B + row) * 32 + f] * wxf;
    }
  }

  // --- W fragments: 32 x uint4 = 128 regs, pinned resident ---
  uint4 wr[32];
  {
    const unsigned short* p0 = WhT + (size_t)n0a * H_SZ + (kq << 3);
#pragma unroll
    for (int kk = 0; kk < 32; ++kk) wr[kk] = *(const uint4*)(p0 + kk * 32);
#pragma unroll
    for (int kk = 0; kk < 32; ++kk)
      asm volatile("" : "+v"(wr[kk].x), "+v"(wr[kk].y),
                        "+v"(wr[kk].z), "+v"(wr[kk].w));
  }

  // staging addrs: 16-row tile, 32 chunks of [16 rows][32 k]; wave w stages
  // chunks w, w+8, w+16, w+24 (4 x 16B per lane), pre-swizzled source
  const int srow = lane >> 2;                        // 0..15
  const int skg  = (lane & 3) ^ ((lane >> 3) & 3);   // XOR by (row>>1)&3
  const int sgbase = srow * H_SZ + (w << 5) + (skg << 3);
  // A-frag read offset within a 512-ushort chunk
  const int q = kq ^ ((col >> 1) & 3);
  const int aoff = col * 32 + (q << 3);
  // y-dot constants: thread (ykc,yf) covers 64 k for feature yf of own row
  const int yf = tid & 31, ykc = tid >> 5;
  const int yrow = slot & 15;
  const int ysw = (slot >> 1) & 3;
  const bool yIsA = (slot < 16);
  const unsigned short* wdp = WdT + (size_t)yf * H_SZ + ykc * 64;

  bool pure = false;
  for (int j = 0; j <= T_SZ; ++j) {
    const unsigned int tgt = (unsigned)(j + 1);
    // ---- wait A: aggregator-broadcast ----
    if (slot == 0 && w == 0) {
      const unsigned int* ap = flags + (((xcd << 5) | (lane & 31)) << 4);
      while (true) {
        unsigned int v = __hip_atomic_load(ap, __ATOMIC_RELAXED,
                                           __HIP_MEMORY_SCOPE_AGENT);
        if (__all(v >= tgt)) break;
        __builtin_amdgcn_s_sleep(1);
      }
      if (lane == 0)
        __hip_atomic_store(epochA, tgt, __ATOMIC_RELAXED,
                           __HIP_MEMORY_SCOPE_AGENT);
    }
    while (__hip_atomic_load(epochA, __ATOMIC_RELAXED,
                             __HIP_MEMORY_SCOPE_AGENT) < tgt)
      __builtin_amdgcn_s_sleep(2);
    if (j == 0) {
      __builtin_amdgcn_fence(__ATOMIC_ACQUIRE, "agent");  // one-time L2 inv
      bool eq = (__hip_atomic_load(&xcctab[((lane & 31) << 3) | xcd],
                                   __ATOMIC_RELAXED,
                                   __HIP_MEMORY_SCOPE_AGENT) == myxcc);
      pure = __all(eq);
    } else if (!pure) {
      __builtin_amdgcn_fence(__ATOMIC_ACQUIRE, "agent");  // fallback: L2 inv
    }
    const unsigned short* hp = (j & 1) ? hbuf1 : hbuf0;
    unsigned short* hn = (j & 1) ? hbuf0 : hbuf1;

    // ---- stage A (32 KB) ----
    {
      const unsigned short* src = hp + (size_t)m0A * H_SZ + sgbase;
#pragma unroll
      for (int it = 0; it < 4; ++it)
        stage16c(src + it * 256, &AbA[it * 4096 + (w << 9)]);
      __syncthreads();                     // AbA ready
    }

    // ---- wait B (aggregator) + early-issue stage B ----
    if (slot == 0 && w == 0) {
      const unsigned int* bp = flags + 4096 + (((xcd << 5) | (lane & 31)) << 4);
      while (true) {
        unsigned int v = __hip_atomic_load(bp, __ATOMIC_RELAXED,
                                           __HIP_MEMORY_SCOPE_AGENT);
        if (__all(v >= tgt)) break;
        __builtin_amdgcn_s_sleep(1);
      }
      if (lane == 0)
        __hip_atomic_store(epochB, tgt, __ATOMIC_RELAXED,
                           __HIP_MEMORY_SCOPE_AGENT);
    }
    while (__hip_atomic_load(epochB, __ATOMIC_RELAXED,
                             __HIP_MEMORY_SCOPE_AGENT) < tgt)
      __builtin_amdgcn_s_sleep(2);
    if (!pure && j > 0)
      __builtin_amdgcn_fence(__ATOMIC_ACQUIRE, "agent");
    {
      const unsigned short* src = hp + (size_t)m0B * H_SZ + sgbase;
#pragma unroll
      for (int it = 0; it < 4; ++it)
        stage16c(src + it * 256, &AbB[it * 4096 + (w << 9)]);
    }

    // ---- y-dot A (A-row blocks): y_{j-1}[m0A+yrow][yf] ----
    if (j >= 1 && yIsA) {
      float acc = 0.f;
#pragma unroll
      for (int c2 = 0; c2 < 2; ++c2) {
        const unsigned short* ab = AbA + (ykc * 2 + c2) * 512 + yrow * 32;
#pragma unroll
        for (int p = 0; p < 4; ++p) {
          uint4 av = *(const uint4*)(ab + (p << 3));
          uint4 wv = *(const uint4*)(wdp + c2 * 32 + ((p ^ ysw) << 3));
          acc += __uint_as_float(av.x << 16) * __uint_as_float(wv.x << 16);
          acc += __uint_as_float(av.x & 0xffff0000u) * __uint_as_float(wv.x & 0xffff0000u);
          acc += __uint_as_float(av.y << 16) * __uint_as_float(wv.y << 16);
          acc += __uint_as_float(av.y & 0xffff0000u) * __uint_as_float(wv.y & 0xffff0000u);
          acc += __uint_as_float(av.z << 16) * __uint_as_float(wv.z << 16);
          acc += __uint_as_float(av.z & 0xffff0000u) * __uint_as_float(wv.z & 0xffff0000u);
          acc += __uint_as_float(av.w << 16) * __uint_as_float(wv.w << 16);
          acc += __uint_as_float(av.w & 0xffff0000u) * __uint_as_float(wv.w & 0xffff0000u);
        }
      }
      ypA[ykc][yf] = acc;
    }

    // ---- GEMM A ----
    if (j < T_SZ) {
      f32x4 accE, accO;
#pragma unroll
      for (int e = 0; e < 4; ++e) {
        accE[e] = (j == 0) ? u0rA[e] : bfv;
        accO[e] = 0.f;
      }
#pragma unroll
      for (int kk = 0; kk < 32; kk += 2) {
        short8 a0 = *(const short8*)(AbA + kk * 512 + aoff);
        short8 a1 = *(const short8*)(AbA + (kk + 1) * 512 + aoff);
        accE = __builtin_amdgcn_mfma_f32_16x16x32_bf16(a0, u4s8(wr[kk]), accE, 0, 0, 0);
        accO = __builtin_amdgcn_mfma_f32_16x16x32_bf16(a1, u4s8(wr[kk + 1]), accO, 0, 0, 0);
      }
#pragma unroll
      for (int e = 0; e < 4; ++e)
        zldsA[g][(kq << 2) + e][nhh + col] = accE[e] + accO[e];
    }
    __syncthreads();                       // zldsA+ypA ready; stage B drained

    if (j < T_SZ) {                        // cell update A
      int m = tid >> 5, cc = tid & 31;
      float zi = zldsA[0][m][cc], zf = zldsA[1][m][cc];
      float zg = zldsA[2][m][cc], zo = zldsA[3][m][cc];
      float iv = sigf(zi), fv = sigf(zf), gv = tanh_fast(zg), ov = sigf(zo);
      float cn = fv * cregA + iv * gv;
      cregA = cn;
      hn[(size_t)(m0A + m) * H_SZ + nh + cc] = f2bf(ov * tanh_fast(cn));
    }
    if (j >= 1 && yIsA && tid < 32) {      // finish y_{j-1} row m0A+yrow
      float s = bd[tid];
#pragma unroll
      for (int kc = 0; kc < 16; ++kc) s += ypA[kc][tid];
      out[(size_t)(m0A + yrow) * (T_SZ * F_SZ) + (size_t)(j - 1) * F_SZ + tid] = s;
    }
    __syncthreads();                       // hA stores drained -> L2
    if (tid == 0 && j < T_SZ) {
      if (pure)
        __hip_atomic_store(arrA, tgt + 1, __ATOMIC_RELAXED,
                           __HIP_MEMORY_SCOPE_AGENT);
      else
        __hip_atomic_store(arrA, tgt + 1, __ATOMIC_RELEASE,
                           __HIP_MEMORY_SCOPE_AGENT);
    }

    // ==== stream B (tile already staged & drained) ====
    if (j >= 1 && !yIsA) {
      float acc = 0.f;
#pragma unroll
      for (int c2 = 0; c2 < 2; ++c2) {
        const unsigned short* ab = AbB + (ykc * 2 + c2) * 512 + yrow * 32;
#pragma unroll
        for (int p = 0; p < 4; ++p) {
          uint4 av = *(const uint4*)(ab + (p << 3));
          uint4 wv = *(const uint4*)(wdp + c2 * 32 + ((p ^ ysw) << 3));
          acc += __uint_as_float(av.x << 16) * __uint_as_float(wv.x << 16);
          acc += __uint_as_float(av.x & 0xffff0000u) * __uint_as_float(wv.x & 0xffff0000u);
          acc += __uint_as_float(av.y << 16) * __uint_as_float(wv.y << 16);
          acc += __uint_as_float(av.y & 0xffff0000u) * __uint_as_float(wv.y & 0xffff0000u);
          acc += __uint_as_float(av.z << 16) * __uint_as_float(wv.z << 16);
          acc += __uint_as_float(av.z & 0xffff0000u) * __uint_as_float(wv.z & 0xffff0000u);
          acc += __uint_as_float(av.w << 16) * __uint_as_float(wv.w << 16);
          acc += __uint_as_float(av.w & 0xffff0000u) * __uint_as_float(wv.w & 0xffff0000u);
        }
      }
      ypB[ykc][yf] = acc;
    }

    if (j < T_SZ) {
      f32x4 accE, accO;
#pragma unroll
      for (int e = 0; e < 4; ++e) {
        accE[e] = (j == 0) ? u0rB[e] : bfv;
        accO[e] = 0.f;
      }
#pragma unroll
      for (int kk = 0; kk < 32; kk += 2) {
        short8 a0 = *(const short8*)(AbB + kk * 512 + aoff);
        short8 a1 = *(const short8*)(AbB + (kk + 1) * 512 + aoff);
        accE = __builtin_amdgcn_mfma_f32_16x16x32_bf16(a0, u4s8(wr[kk]), accE, 0, 0, 0);
        accO = __builtin_amdgcn_mfma_f32_16x16x32_bf16(a1, u4s8(wr[kk + 1]), accO, 0, 0, 0);
      }
      if (j == 0) {                        // switch to folded weights (once)
        const unsigned short* p0 = WeffT + (size_t)n0a * H_SZ + (kq << 3);
#pragma unroll
        for (int kk = 0; kk < 32; ++kk) wr[kk] = *(const uint4*)(p0 + kk * 32);
#pragma unroll
        for (int kk = 0; kk < 32; ++kk)
          asm volatile("" : "+v"(wr[kk].x), "+v"(wr[kk].y),
                            "+v"(wr[kk].z), "+v"(wr[kk].w));
      }
#pragma unroll
      for (int e = 0; e < 4; ++e)
        zldsB[g][(kq << 2) + e][nhh + col] = accE[e] + accO[e];
    }
    __syncthreads();                       // zldsB+ypB ready

    if (j < T_SZ) {                        // cell update B
      int m = tid >> 5, cc = tid & 31;
      float zi = zldsB[0][m][cc], zf = zldsB[1][m][cc];
      float zg = zldsB[2][m][cc], zo = zldsB[3][m][cc];
      float iv = sigf(zi), fv = sigf(zf), gv = tanh_fast(zg), ov = sigf(zo);
      float cn = fv * cregB + iv * gv;
      cregB = cn;
      hn[(size_t)(m0B + m) * H_SZ + nh + cc] = f2bf(ov * tanh_fast(cn));
    }
    if (j >= 1 && !yIsA && tid < 32) {     // finish y_{j-1} row m0B+yrow
      float s = bd[tid];
#pragma unroll
      for (int kc = 0; kc < 16; ++kc) s += ypB[kc][tid];
      out[(size_t)(m0B + yrow) * (T_SZ * F_SZ) + (size_t)(j - 1) * F_SZ + tid] = s;
    }
    __syncthreads();                       // hB stores drained -> L2
    if (tid == 0 && j < T_SZ) {
      if (pure)
        __hip_atomic_store(arrB, tgt + 1, __ATOMIC_RELAXED,
                           __HIP_MEMORY_SCOPE_AGENT);
      else
        __hip_atomic_store(arrB, tgt + 1, __ATOMIC_RELEASE,
                           __HIP_MEMORY_SCOPE_AGENT);
    }
  }
}

// ---------------------------------------------------------------------------
extern "C" void kernel_launch(void* const* d_in, const int* in_sizes, int n_in,
                              void* d_out, int out_size, void* d_ws, size_t ws_size,
                              hipStream_t stream)
{
  const float* x0 = (const float*)d_in[0];   // (256,1,32)
  const float* h0 = (const float*)d_in[1];   // (256,1024)
  const float* c0 = (const float*)d_in[2];
  // d_in[3] targets unused
  const float* Wx = (const float*)d_in[4];   // (32,4096)
  const float* Wh = (const float*)d_in[5];   // (1024,4096)
  const float* bv = (const float*)d_in[6];   // (4096)
  const float* Wd = (const float*)d_in[7];   // (1024,32)
  const float* bd = (const float*)d_in[8];   // (32)
  float* out = (float*)d_out;                // (256,96,32) fp32

  char* p = (char*)d_ws;
  unsigned short* WeffT = (unsigned short*)p; p += (size_t)NG * H_SZ * 2;   // 8 MB
  unsigned short* WhT   = (unsigned short*)p; p += (size_t)NG * H_SZ * 2;   // 8 MB
  unsigned short* WdT   = (unsigned short*)p; p += (size_t)F_SZ * H_SZ * 2; // 64 KB
  unsigned short* hb0   = (unsigned short*)p; p += (size_t)B_SZ * H_SZ * 2; // 512 KB
  unsigned short* hb1   = (unsigned short*)p; p += (size_t)B_SZ * H_SZ * 2; // 512 KB
  unsigned int* flags   = (unsigned int*)p;  p += 8704 * 4;  // arr/epoch/xcc
  (void)ws_size; (void)in_sizes; (void)n_in; (void)out_size;

  k_prep_w<<<dim3(513), dim3(256), 0, stream>>>(Wx, Wh, Wd, WeffT, WhT, WdT, flags);

  k_persist<<<dim3(256), dim3(512), 0, stream>>>(
      WeffT, WhT, x0, h0, c0, Wx, bv, bd, WdT, hb0, hb1, out, flags);
}

// Round 15
// 709.420 us; speedup vs baseline: 1.3316x; 1.1615x over previous
//
#include <hip/hip_runtime.h>
#include <hip/hip_bf16.h>
#include <stdint.h>

#define B_SZ 256
#define H_SZ 1024
#define NG   4096   // 4*H
#define F_SZ 32
#define T_SZ 96

typedef __attribute__((ext_vector_type(8))) short short8;
typedef __attribute__((ext_vector_type(4))) float f32x4;

__device__ __forceinline__ unsigned short f2bf(float x) {
  unsigned int u = __float_as_uint(x);
  u += 0x7fffu + ((u >> 16) & 1u);   // RNE
  return (unsigned short)(u >> 16);
}
__device__ __forceinline__ float sigf(float x) {
  float e = __expf(-x);
  return __builtin_amdgcn_rcpf(1.f + e);
}
__device__ __forceinline__ float tanh_fast(float x) {
  float e = __expf(-2.f * fabsf(x));
  float t = (1.f - e) * __builtin_amdgcn_rcpf(1.f + e);
  return copysignf(t, x);
}
// SC0 staging load: L1-bypass, L2-coherent (fresh same-XCD data, no inv needed)
__device__ __forceinline__ void stage16c(const void* g, void* l) {
  __builtin_amdgcn_global_load_lds(
      (const __attribute__((address_space(1))) void*)g,
      (__attribute__((address_space(3))) void*)l, 16, 0, 1 /*sc0*/);
}
__device__ __forceinline__ short8 u4s8(uint4 v) {
  union { uint4 u; short8 s; } c; c.u = v; return c.s;
}

// ---------------------------------------------------------------------------
// Prep: WeffT[n][k] = (W_h + W_dense@W_x)^T, WhT[n][k], WdT[f][k] (bf16),
// single pass over W_h. Block 512: WdT + zero flags (A,B) + xcctab.
// ---------------------------------------------------------------------------
__global__ __launch_bounds__(256) void k_prep_w(
    const float* __restrict__ Wx, const float* __restrict__ Wh,
    const float* __restrict__ Wd,
    unsigned short* __restrict__ WeffT, unsigned short* __restrict__ WhT,
    unsigned short* __restrict__ WdT, unsigned int* __restrict__ flags)
{
  int tid = threadIdx.x;
  if (blockIdx.x == 512) {               // WdT; zero flagsA/flagsB/xcctab
    for (int i = 0; i < 33; ++i) flags[i * 256 + tid] = 0u;
    for (int i = 0; i < 128; ++i) {
      int idx = i * 256 + tid;
      int f = idx >> 10, k = idx & 1023;
      WdT[idx] = f2bf(Wd[k * 32 + f]);
    }
    return;
  }
  __shared__ float wx[32 * 256];              // 32 KB: W_x[f][n-tile]
  __shared__ unsigned short resE[32 * 256];   // 16 KB
  __shared__ unsigned short resH[32 * 256];   // 16 KB
  int kt = blockIdx.x & 31, nt = blockIdx.x >> 5;
  int k0 = kt * 32, n0 = nt * 256;
  for (int i = 0; i < 32; ++i) {
    int lin = i * 256 + tid;
    wx[lin] = Wx[(size_t)(lin >> 8) * NG + n0 + (lin & 255)];
  }
  __syncthreads();
  for (int kr = 0; kr < 32; ++kr) {
    int k = k0 + kr;
    float v = Wh[(size_t)k * NG + n0 + tid];
    float acc = 0.f;
#pragma unroll
    for (int f = 0; f < 32; ++f) acc += Wd[k * 32 + f] * wx[f * 256 + tid];
    resH[kr * 256 + tid] = f2bf(v);
    resE[kr * 256 + tid] = f2bf(v + acc);
  }
  __syncthreads();
#pragma unroll
  for (int pass = 0; pass < 2; ++pass) {
    const unsigned short* res = pass ? resH : resE;
    unsigned short* dst = (pass ? WhT : WeffT) + (size_t)(n0 + tid) * H_SZ + k0;
    unsigned int vals[16];
#pragma unroll
    for (int p = 0; p < 16; ++p)
      vals[p] = (unsigned int)res[(2 * p) * 256 + tid] |
                ((unsigned int)res[(2 * p + 1) * 256 + tid] << 16);
#pragma unroll
    for (int qd = 0; qd < 4; ++qd) {
      uint4 v4; v4.x = vals[4*qd]; v4.y = vals[4*qd+1]; v4.z = vals[4*qd+2]; v4.w = vals[4*qd+3];
      ((uint4*)dst)[qd] = v4;
    }
  }
}

// ---------------------------------------------------------------------------
// Persistent LSTM, DUAL-STREAM latency hiding. 256 blocks x 512 threads,
// 1 block/CU (85 KB LDS). XCD group (b&7) owns 32 batch rows, split into two
// independent 16-row streams A/B; its 32 blocks (slot=b>>3) each own 32
// h-cols of both. Per step: pollA -> stageA -> [pollB + issue stageB under
// A's MFMA] -> computeA -> releaseA -> computeB (tile already resident) ->
// releaseB. This is the measured-best structure (r10: 714us); r11-r14
// variants (wide-N 4-wave, single-counter, segmented-amp, aggregator
// broadcast) all measured neutral-or-worse and are reverted. Measured cost
// structure: parallel-store barrier generation ~1-1.5us, serialized-RMW
// generation 4.5us (r13), each extra hop +0.6us (r14); step = 2 overlapped
// generations + ~2.5us compute = 7.4us, vs ~5-6us optimistic floor.
// W pinned register-resident (asm opacity); pure-XCD coherence (r7-verified):
// RELAXED agent flag store/polls, SC0 staging reads; agent-fence fallback.
// ---------------------------------------------------------------------------
__global__ __launch_bounds__(512, 2) void k_persist(
    const unsigned short* __restrict__ WeffT,
    const unsigned short* __restrict__ WhT,
    const float* __restrict__ x0,
    const float* __restrict__ h0,
    const float* __restrict__ c0,
    const float* __restrict__ Wx,
    const float* __restrict__ bvec,
    const float* __restrict__ bd,
    const unsigned short* __restrict__ WdT,
    unsigned short* __restrict__ hbuf0,
    unsigned short* __restrict__ hbuf1,
    float* __restrict__ out,
    unsigned int* __restrict__ flags)
{
  const int b = blockIdx.x;
  const int xcd = b & 7, slot = b >> 3;    // data-layout grouping
  const int m0A = xcd << 5;                // stream A: rows m0A..m0A+15
  const int m0B = m0A + 16;                // stream B: rows m0B..m0B+15
  const int nh = slot << 5;                // 32 h-cols per block
  const int tid = threadIdx.x, lane = tid & 63, w = tid >> 6;
  const int g = w >> 1;                    // gate
  const int nhh = (w & 1) << 4;            // 16-col half

  __shared__ unsigned short AbA[32 * 512]; // 32 KB stream-A h tile (swizzled)
  __shared__ unsigned short AbB[32 * 512]; // 32 KB stream-B h tile
  __shared__ float zldsA[4][16][33];       // gate exchange A
  __shared__ float zldsB[4][16][33];       // gate exchange B
  __shared__ float ypA[16][32];            // y partials A
  __shared__ float ypB[16][32];            // y partials B

  unsigned int* xcctab = flags + 8192;
  unsigned int myxcc;
  asm volatile("s_getreg_b32 %0, hwreg(HW_REG_XCC_ID)" : "=s"(myxcc));
  myxcc &= 15u;

  // --- init: h0 slices -> bf16, c0 -> registers (1 cell/thread/stream) ---
  float cregA, cregB;
  {
    int m = tid >> 5, cc = tid & 31;
    size_t giA = (size_t)(m0A + m) * H_SZ + nh + cc;
    size_t giB = (size_t)(m0B + m) * H_SZ + nh + cc;
    hbuf0[giA] = f2bf(h0[giA]);
    hbuf0[giB] = f2bf(h0[giB]);
    cregA = c0[giA];
    cregB = c0[giB];
  }
  __syncthreads();                         // per-wave vmcnt drained -> L2
  unsigned int* myflagA = flags + (((xcd << 5) | slot) << 4);  // 64B stride
  unsigned int* myflagB = myflagA + 4096;
  if (tid == 0) {
    __hip_atomic_store(&xcctab[b], myxcc, __ATOMIC_RELAXED,
                       __HIP_MEMORY_SCOPE_AGENT);
    __hip_atomic_store(myflagA, 1u, __ATOMIC_RELEASE, __HIP_MEMORY_SCOPE_AGENT);
    __hip_atomic_store(myflagB, 1u, __ATOMIC_RELEASE, __HIP_MEMORY_SCOPE_AGENT);
  }

  // --- per-lane bias: bfv (steady), u0rA/u0rB (step 0, per-row) ---
  const int col = lane & 15;
  const int kq = lane >> 4;
  const int n0a = (g << 10) + nh + nhh + col;
  float bfv = bvec[n0a];
  float u0rA[4], u0rB[4];
#pragma unroll
  for (int e = 0; e < 4; ++e) { u0rA[e] = bfv; u0rB[e] = bfv; }
  for (int f = 0; f < 32; ++f) {
    float wxf = Wx[(size_t)f * NG + n0a];
    bfv += bd[f] * wxf;
#pragma unroll
    for (int e = 0; e < 4; ++e) {
      int row = (kq << 2) + e;
      u0rA[e] += x0[(m0A + row) * 32 + f] * wxf;
      u0rB[e] += x0[(m0B + row) * 32 + f] * wxf;
    }
  }

  // --- W fragments: 32 x uint4 = 128 regs, pinned resident ---
  uint4 wr[32];
  {
    const unsigned short* p0 = WhT + (size_t)n0a * H_SZ + (kq << 3);
#pragma unroll
    for (int kk = 0; kk < 32; ++kk) wr[kk] = *(const uint4*)(p0 + kk * 32);
#pragma unroll
    for (int kk = 0; kk < 32; ++kk)
      asm volatile("" : "+v"(wr[kk].x), "+v"(wr[kk].y),
                        "+v"(wr[kk].z), "+v"(wr[kk].w));
  }

  // staging addrs: 16-row tile, 32 chunks of [16 rows][32 k]; wave w stages
  // chunks w, w+8, w+16, w+24 (4 x 16B per lane), pre-swizzled source
  const int srow = lane >> 2;                        // 0..15
  const int skg  = (lane & 3) ^ ((lane >> 3) & 3);   // XOR by (row>>1)&3
  const int sgbase = srow * H_SZ + (w << 5) + (skg << 3);
  // A-frag read offset within a 512-ushort chunk
  const int q = kq ^ ((col >> 1) & 3);
  const int aoff = col * 32 + (q << 3);
  // y-dot constants: thread (ykc,yf) covers 64 k for feature yf of own row
  const int yf = tid & 31, ykc = tid >> 5;
  const int yrow = slot & 15;
  const int ysw = (slot >> 1) & 3;
  const bool yIsA = (slot < 16);
  const unsigned short* wdp = WdT + (size_t)yf * H_SZ + ykc * 64;
  // poll pointers: member (lane&31) of own group
  const unsigned int* pollpA = flags + (((xcd << 5) | (lane & 31)) << 4);
  const unsigned int* pollpB = pollpA + 4096;

  bool pure = false;
  for (int j = 0; j <= T_SZ; ++j) {
    const unsigned int tgt = (unsigned)(j + 1);
    // ---- poll A ----
    while (true) {
      unsigned int v = __hip_atomic_load(pollpA, __ATOMIC_RELAXED,
                                         __HIP_MEMORY_SCOPE_AGENT);
      if (__all(v >= tgt)) break;
      __builtin_amdgcn_s_sleep(1);
    }
    if (j == 0) {
      __builtin_amdgcn_fence(__ATOMIC_ACQUIRE, "agent");  // one-time L2 inv
      bool eq = (__hip_atomic_load(&xcctab[((lane & 31) << 3) | xcd],
                                   __ATOMIC_RELAXED,
                                   __HIP_MEMORY_SCOPE_AGENT) == myxcc);
      pure = __all(eq);
    } else if (!pure) {
      __builtin_amdgcn_fence(__ATOMIC_ACQUIRE, "agent");
    }
    const unsigned short* hp = (j & 1) ? hbuf1 : hbuf0;
    unsigned short* hn = (j & 1) ? hbuf0 : hbuf1;

    // ---- stage A (32 KB) ----
    {
      const unsigned short* src = hp + (size_t)m0A * H_SZ + sgbase;
#pragma unroll
      for (int it = 0; it < 4; ++it)
        stage16c(src + it * 256, &AbA[it * 4096 + (w << 9)]);
      __syncthreads();                     // AbA ready
    }

    // ---- poll B + early-issue stage B (completes under A's compute) ----
    while (true) {
      unsigned int v = __hip_atomic_load(pollpB, __ATOMIC_RELAXED,
                                         __HIP_MEMORY_SCOPE_AGENT);
      if (__all(v >= tgt)) break;
      __builtin_amdgcn_s_sleep(1);
    }
    if (!pure && j > 0)
      __builtin_amdgcn_fence(__ATOMIC_ACQUIRE, "agent");
    {
      const unsigned short* src = hp + (size_t)m0B * H_SZ + sgbase;
#pragma unroll
      for (int it = 0; it < 4; ++it)
        stage16c(src + it * 256, &AbB[it * 4096 + (w << 9)]);
    }

    // ---- y-dot A (A-row blocks): y_{j-1}[m0A+yrow][yf] ----
    if (j >= 1 && yIsA) {
      float acc = 0.f;
#pragma unroll
      for (int c2 = 0; c2 < 2; ++c2) {
        const unsigned short* ab = AbA + (ykc * 2 + c2) * 512 + yrow * 32;
#pragma unroll
        for (int p = 0; p < 4; ++p) {
          uint4 av = *(const uint4*)(ab + (p << 3));
          uint4 wv = *(const uint4*)(wdp + c2 * 32 + ((p ^ ysw) << 3));
          acc += __uint_as_float(av.x << 16) * __uint_as_float(wv.x << 16);
          acc += __uint_as_float(av.x & 0xffff0000u) * __uint_as_float(wv.x & 0xffff0000u);
          acc += __uint_as_float(av.y << 16) * __uint_as_float(wv.y << 16);
          acc += __uint_as_float(av.y & 0xffff0000u) * __uint_as_float(wv.y & 0xffff0000u);
          acc += __uint_as_float(av.z << 16) * __uint_as_float(wv.z << 16);
          acc += __uint_as_float(av.z & 0xffff0000u) * __uint_as_float(wv.z & 0xffff0000u);
          acc += __uint_as_float(av.w << 16) * __uint_as_float(wv.w << 16);
          acc += __uint_as_float(av.w & 0xffff0000u) * __uint_as_float(wv.w & 0xffff0000u);
        }
      }
      ypA[ykc][yf] = acc;
    }

    // ---- GEMM A ----
    if (j < T_SZ) {
      f32x4 accE, accO;
#pragma unroll
      for (int e = 0; e < 4; ++e) {
        accE[e] = (j == 0) ? u0rA[e] : bfv;
        accO[e] = 0.f;
      }
#pragma unroll
      for (int kk = 0; kk < 32; kk += 2) {
        short8 a0 = *(const short8*)(AbA + kk * 512 + aoff);
        short8 a1 = *(const short8*)(AbA + (kk + 1) * 512 + aoff);
        accE = __builtin_amdgcn_mfma_f32_16x16x32_bf16(a0, u4s8(wr[kk]), accE, 0, 0, 0);
        accO = __builtin_amdgcn_mfma_f32_16x16x32_bf16(a1, u4s8(wr[kk + 1]), accO, 0, 0, 0);
      }
#pragma unroll
      for (int e = 0; e < 4; ++e)
        zldsA[g][(kq << 2) + e][nhh + col] = accE[e] + accO[e];
    }
    __syncthreads();                       // zldsA+ypA ready; stage B drained

    if (j < T_SZ) {                        // cell update A
      int m = tid >> 5, cc = tid & 31;
      float zi = zldsA[0][m][cc], zf = zldsA[1][m][cc];
      float zg = zldsA[2][m][cc], zo = zldsA[3][m][cc];
      float iv = sigf(zi), fv = sigf(zf), gv = tanh_fast(zg), ov = sigf(zo);
      float cn = fv * cregA + iv * gv;
      cregA = cn;
      hn[(size_t)(m0A + m) * H_SZ + nh + cc] = f2bf(ov * tanh_fast(cn));
    }
    if (j >= 1 && yIsA && tid < 32) {      // finish y_{j-1} row m0A+yrow
      float s = bd[tid];
#pragma unroll
      for (int kc = 0; kc < 16; ++kc) s += ypA[kc][tid];
      out[(size_t)(m0A + yrow) * (T_SZ * F_SZ) + (size_t)(j - 1) * F_SZ + tid] = s;
    }
    __syncthreads();                       // hA stores drained -> L2
    if (tid == 0 && j < T_SZ) {
      if (pure)
        __hip_atomic_store(myflagA, tgt + 1, __ATOMIC_RELAXED,
                           __HIP_MEMORY_SCOPE_AGENT);
      else
        __hip_atomic_store(myflagA, tgt + 1, __ATOMIC_RELEASE,
                           __HIP_MEMORY_SCOPE_AGENT);
    }

    // ==== stream B (tile already staged & drained) ====
    if (j >= 1 && !yIsA) {
      float acc = 0.f;
#pragma unroll
      for (int c2 = 0; c2 < 2; ++c2) {
        const unsigned short* ab = AbB + (ykc * 2 + c2) * 512 + yrow * 32;
#pragma unroll
        for (int p = 0; p < 4; ++p) {
          uint4 av = *(const uint4*)(ab + (p << 3));
          uint4 wv = *(const uint4*)(wdp + c2 * 32 + ((p ^ ysw) << 3));
          acc += __uint_as_float(av.x << 16) * __uint_as_float(wv.x << 16);
          acc += __uint_as_float(av.x & 0xffff0000u) * __uint_as_float(wv.x & 0xffff0000u);
          acc += __uint_as_float(av.y << 16) * __uint_as_float(wv.y << 16);
          acc += __uint_as_float(av.y & 0xffff0000u) * __uint_as_float(wv.y & 0xffff0000u);
          acc += __uint_as_float(av.z << 16) * __uint_as_float(wv.z << 16);
          acc += __uint_as_float(av.z & 0xffff0000u) * __uint_as_float(wv.z & 0xffff0000u);
          acc += __uint_as_float(av.w << 16) * __uint_as_float(wv.w << 16);
          acc += __uint_as_float(av.w & 0xffff0000u) * __uint_as_float(wv.w & 0xffff0000u);
        }
      }
      ypB[ykc][yf] = acc;
    }

    if (j < T_SZ) {
      f32x4 accE, accO;
#pragma unroll
      for (int e = 0; e < 4; ++e) {
        accE[e] = (j == 0) ? u0rB[e] : bfv;
        accO[e] = 0.f;
      }
#pragma unroll
      for (int kk = 0; kk < 32; kk += 2) {
        short8 a0 = *(const short8*)(AbB + kk * 512 + aoff);
        short8 a1 = *(const short8*)(AbB + (kk + 1) * 512 + aoff);
        accE = __builtin_amdgcn_mfma_f32_16x16x32_bf16(a0, u4s8(wr[kk]), accE, 0, 0, 0);
        accO = __builtin_amdgcn_mfma_f32_16x16x32_bf16(a1, u4s8(wr[kk + 1]), accO, 0, 0, 0);
      }
      if (j == 0) {                        // switch to folded weights (once)
        const unsigned short* p0 = WeffT + (size_t)n0a * H_SZ + (kq << 3);
#pragma unroll
        for (int kk = 0; kk < 32; ++kk) wr[kk] = *(const uint4*)(p0 + kk * 32);
#pragma unroll
        for (int kk = 0; kk < 32; ++kk)
          asm volatile("" : "+v"(wr[kk].x), "+v"(wr[kk].y),
                            "+v"(wr[kk].z), "+v"(wr[kk].w));
      }
#pragma unroll
      for (int e = 0; e < 4; ++e)
        zldsB[g][(kq << 2) + e][nhh + col] = accE[e] + accO[e];
    }
    __syncthreads();                       // zldsB+ypB ready

    if (j < T_SZ) {                        // cell update B
      int m = tid >> 5, cc = tid & 31;
      float zi = zldsB[0][m][cc], zf = zldsB[1][m][cc];
      float zg = zldsB[2][m][cc], zo = zldsB[3][m][cc];
      float iv = sigf(zi), fv = sigf(zf), gv = tanh_fast(zg), ov = sigf(zo);
      float cn = fv * cregB + iv * gv;
      cregB = cn;
      hn[(size_t)(m0B + m) * H_SZ + nh + cc] = f2bf(ov * tanh_fast(cn));
    }
    if (j >= 1 && !yIsA && tid < 32) {     // finish y_{j-1} row m0B+yrow
      float s = bd[tid];
#pragma unroll
      for (int kc = 0; kc < 16; ++kc) s += ypB[kc][tid];
      out[(size_t)(m0B + yrow) * (T_SZ * F_SZ) + (size_t)(j - 1) * F_SZ + tid] = s;
    }
    __syncthreads();                       // hB stores drained -> L2
    if (tid == 0 && j < T_SZ) {
      if (pure)
        __hip_atomic_store(myflagB, tgt + 1, __ATOMIC_RELAXED,
                           __HIP_MEMORY_SCOPE_AGENT);
      else
        __hip_atomic_store(myflagB, tgt + 1, __ATOMIC_RELEASE,
                           __HIP_MEMORY_SCOPE_AGENT);
    }
  }
}

// ---------------------------------------------------------------------------
extern "C" void kernel_launch(void* const* d_in, const int* in_sizes, int n_in,
                              void* d_out, int out_size, void* d_ws, size_t ws_size,
                              hipStream_t stream)
{
  const float* x0 = (const float*)d_in[0];   // (256,1,32)
  const float* h0 = (const float*)d_in[1];   // (256,1024)
  const float* c0 = (const float*)d_in[2];
  // d_in[3] targets unused
  const float* Wx = (const float*)d_in[4];   // (32,4096)
  const float* Wh = (const float*)d_in[5];   // (1024,4096)
  const float* bv = (const float*)d_in[6];   // (4096)
  const float* Wd = (const float*)d_in[7];   // (1024,32)
  const float* bd = (const float*)d_in[8];   // (32)
  float* out = (float*)d_out;                // (256,96,32) fp32

  char* p = (char*)d_ws;
  unsigned short* WeffT = (unsigned short*)p; p += (size_t)NG * H_SZ * 2;   // 8 MB
  unsigned short* WhT   = (unsigned short*)p; p += (size_t)NG * H_SZ * 2;   // 8 MB
  unsigned short* WdT   = (unsigned short*)p; p += (size_t)F_SZ * H_SZ * 2; // 64 KB
  unsigned short* hb0   = (unsigned short*)p; p += (size_t)B_SZ * H_SZ * 2; // 512 KB
  unsigned short* hb1   = (unsigned short*)p; p += (size_t)B_SZ * H_SZ * 2; // 512 KB
  unsigned int* flags   = (unsigned int*)p;  p += 8704 * 4;  // flagsA/B + xcctab
  (void)ws_size; (void)in_sizes; (void)n_in; (void)out_size;

  k_prep_w<<<dim3(513), dim3(256), 0, stream>>>(Wx, Wh, Wd, WeffT, WhT, WdT, flags);

  k_persist<<<dim3(256), dim3(512), 0, stream>>>(
      WeffT, WhT, x0, h0, c0, Wx, bv, bd, WdT, hb0, hb1, out, flags);
}